// Round 8
// baseline (504.053 us; speedup 1.0000x reference)
//
#include <hip/hip_runtime.h>

// Problem constants (match reference)
constexpr int N  = 100000;   // nodes
constexpr int E  = 1600000;  // edges
constexpr int H  = 128;      // hidden
constexpr int NB = 4096;     // root pairs
constexpr int HOPS = 3;
constexpr int RCAP = 596 * 128;   // 76288 >= 4096 + relevant-edge unique sources (+8 sigma)

// Swizzled converted-weight buffer (element offsets into whi/wlo ushort arrays).
// tile(c,t) = 16 cols x 32 k; element (n,k), n=c*16+nl, k=t*32+quad*8+e at
// (t*numC+c)*512 + lane*8 + e  -> B-fragment load = one coalesced dwordx4.
constexpr int WOFF_L1  = 0;                      // numC=8,  numT=8  (K=256)
constexpr int WOFF_GAT = 32768;                  // 3 x numC=8,  numT=4
constexpr int WOFF_CAT = 81920;                  // 3 x numC=32, numT=12 (gate-perm)
constexpr int WOFF_L2  = 671744;                 // numC=8,  numT=4
constexpr int WTOT     = 688128;
constexpr int WCONV_BLOCKS = (WTOT + 255) / 256; // 2688

// ---------------- workspace layout (byte offsets, 256B aligned) ---------------
constexpr size_t ALIGN = 256;
constexpr size_t alup(size_t x) { return (x + ALIGN - 1) & ~(ALIGN - 1); }

constexpr size_t OFF_XP      = 0;                                        // [RCAP,128] f32
constexpr size_t OFF_SSRC    = alup(OFF_XP + (size_t)RCAP * H * 4);      // [3][RCAP] f32
constexpr size_t OFF_SDST    = alup(OFF_SSRC + (size_t)3 * RCAP * 4);    // [3][RCAP] f32
constexpr size_t OFF_WVEC    = alup(OFF_SDST + (size_t)3 * RCAP * 4);    // [6][128] f32
constexpr size_t OFF_SELMAP  = alup(OFF_WVEC + 6 * H * 4);               // [N] int
constexpr size_t OFF_NEEDED  = alup(OFF_SELMAP + (size_t)N * 4);         // [N] int
constexpr size_t OFF_ROWID   = alup(OFF_NEEDED + (size_t)N * 4);         // [N] int
constexpr size_t OFF_NODELST = alup(OFF_ROWID + (size_t)N * 4);          // [4096] int
constexpr size_t OFF_ROWLST  = alup(OFF_NODELST + NB * 4);               // [RCAP] int
constexpr size_t OFF_CNT     = alup(OFF_ROWLST + (size_t)RCAP * 4);      // [64] int
constexpr size_t OFF_DEG     = alup(OFF_CNT + 256);                      // [4096] int
constexpr size_t OFF_OFFS    = alup(OFF_DEG + NB * 4);                   // [4097] int
constexpr size_t OFF_CURSOR  = alup(OFF_OFFS + (NB + 1) * 4);            // [4096] int
constexpr size_t OFF_ESORT   = alup(OFF_CURSOR + NB * 4);                // [E] int
constexpr size_t OFF_AGGXH   = alup(OFF_ESORT + (size_t)E * 4);          // [3][4096][128] us
constexpr size_t OFF_AGGXL   = alup(OFF_AGGXH + (size_t)3 * NB * H * 2);
constexpr size_t OFF_XSH     = alup(OFF_AGGXL + (size_t)3 * NB * H * 2); // [4096][128] us
constexpr size_t OFF_XSL     = alup(OFF_XSH + (size_t)NB * H * 2);
constexpr size_t OFF_L2OUT   = alup(OFF_XSL + (size_t)NB * H * 2);       // [4096][128] f32
constexpr size_t OFF_WHI     = alup(OFF_L2OUT + (size_t)NB * H * 4);     // [WTOT] us
constexpr size_t OFF_WLO     = alup(OFF_WHI + (size_t)WTOT * 2);         // [WTOT] us

__device__ __forceinline__ float lrelu(float v) { return v > 0.f ? v : 0.2f * v; }
__device__ __forceinline__ float sigmoidf_(float v) { return 1.f / (1.f + __expf(-v)); }

__device__ __forceinline__ unsigned short f2bf(float f) {
  unsigned u = __float_as_uint(f);
  unsigned r = (u + 0x7FFFu + ((u >> 16) & 1u)) >> 16;
  return (unsigned short)r;
}
__device__ __forceinline__ float bf2f(unsigned short h) {
  return __uint_as_float((unsigned)h << 16);
}
__device__ __forceinline__ void split_rne(float f, unsigned short& hi, unsigned short& lo) {
  unsigned short hh = f2bf(f);
  hi = hh;
  lo = f2bf(f - bf2f(hh));
}
// 4-op truncation split (lin1 hot path); pointer outs (vector elems can't bind refs)
__device__ __forceinline__ void split_trunc(float f, short* hi, short* lo) {
  unsigned u = __float_as_uint(f);
  *hi = (short)(u >> 16);
  float r = f - __uint_as_float(u & 0xFFFF0000u);
  *lo = (short)(__float_as_uint(r) >> 16);
}

typedef short bf16x8 __attribute__((ext_vector_type(8)));
typedef float f32x4  __attribute__((ext_vector_type(4)));

#define MFMA3(ACC, AH, AL, BH, BL)                                               \
  ACC = __builtin_amdgcn_mfma_f32_16x16x32_bf16(AH, BH, ACC, 0, 0, 0);           \
  ACC = __builtin_amdgcn_mfma_f32_16x16x32_bf16(AH, BL, ACC, 0, 0, 0);           \
  ACC = __builtin_amdgcn_mfma_f32_16x16x32_bf16(AL, BH, ACC, 0, 0, 0);

// ---------------- mega: wvec + weight-convert + init sweeps (one dispatch) -----
__global__ void mega_prep(const float* __restrict__ gat_W,
                          const float* __restrict__ a_src,
                          const float* __restrict__ a_dst,
                          float* __restrict__ wvec,
                          const float* __restrict__ lin1_W,
                          const float* __restrict__ Wih,
                          const float* __restrict__ Whh,
                          const float* __restrict__ lin2_W,
                          unsigned short* __restrict__ whi,
                          unsigned short* __restrict__ wlo,
                          int* __restrict__ sel_map, int* __restrict__ needed,
                          int* __restrict__ deg, int* __restrict__ cursor,
                          int* __restrict__ cnt) {
  if (blockIdx.x < 6) {
    int i = blockIdx.x >> 1, which = blockIdx.x & 1;
    int k = threadIdx.x;
    __shared__ float av[H];
    if (k < H) av[k] = which ? a_dst[i * H + k] : a_src[i * H + k];
    __syncthreads();
    if (k >= H) return;
    const float* Wr = gat_W + (size_t)i * H * H + (size_t)k * H;
    float s = 0.f;
    #pragma unroll 8
    for (int j = 0; j < H; j++) s = fmaf(Wr[j], av[j], s);
    wvec[(i * 2 + which) * H + k] = s;
    return;
  }
  if (blockIdx.x < 6 + WCONV_BLOCKS) {
    int idx = (blockIdx.x - 6) * 256 + threadIdx.x;
    if (idx >= WTOT) return;
    float v;
    if (idx < WOFF_GAT) {                      // lin1: numC=8, K=256
      int rel = idx;
      int e = rel & 7, lane = (rel >> 3) & 63, tile = rel >> 9;
      int nl = lane & 15, quad = lane >> 4;
      int c = tile & 7, t = tile >> 3;
      int n = c * 16 + nl, k = t * 32 + quad * 8 + e;
      v = lin1_W[k * 128 + n];
    } else if (idx < WOFF_CAT) {               // gat: 3 x numC=8, K=128
      int rel = idx - WOFF_GAT;
      int hop = rel / 16384; rel %= 16384;
      int e = rel & 7, lane = (rel >> 3) & 63, tile = rel >> 9;
      int nl = lane & 15, quad = lane >> 4;
      int c = tile & 7, t = tile >> 3;
      int n = c * 16 + nl, k = t * 32 + quad * 8 + e;
      v = gat_W[hop * 16384 + k * 128 + n];
    } else if (idx < WOFF_L2) {                // CAT: 3 x numC=32, K=384, gate-perm
      int rel = idx - WOFF_CAT;
      int hop = rel / 196608; rel %= 196608;
      int e = rel & 7, lane = (rel >> 3) & 63, tile = rel >> 9;
      int nl = lane & 15, quad = lane >> 4;
      int c = tile & 31, t = tile >> 5;
      int ftile = c >> 2, g = c & 3;
      int col = g * 128 + ftile * 16 + nl;
      int k = t * 32 + quad * 8 + e;
      v = (k < 256) ? Wih[hop * 131072 + k * 512 + col]
                    : Whh[hop * 65536 + (k - 256) * 512 + col];
    } else {                                   // lin2: numC=8, K=128
      int rel = idx - WOFF_L2;
      int e = rel & 7, lane = (rel >> 3) & 63, tile = rel >> 9;
      int nl = lane & 15, quad = lane >> 4;
      int c = tile & 7, t = tile >> 3;
      int n = c * 16 + nl, k = t * 32 + quad * 8 + e;
      v = lin2_W[k * 128 + n];
    }
    unsigned short hh, ll;
    split_rne(v, hh, ll);
    whi[idx] = hh;
    wlo[idx] = ll;
    return;
  }
  // init sweeps
  int i = (blockIdx.x - 6 - WCONV_BLOCKS) * 256 + threadIdx.x;
  int stride = 256 * 256;
  for (int n = i; n < N; n += stride) { sel_map[n] = -1; needed[n] = 0; }
  for (int n = i; n < NB; n += stride) { deg[n] = 0; cursor[n] = 0; }
  if (i < 64) cnt[i] = 0;
}

// ---------------- roots: mark + compact-id assign ------------------------------
__global__ void roots_assign(const int* __restrict__ root, const int* __restrict__ aggp,
                             int* __restrict__ sel_map, int* __restrict__ node_list,
                             int* __restrict__ cnt, int* __restrict__ needed) {
  int b = blockIdx.x * 256 + threadIdx.x;
  if (b >= NB) return;
  int node = root[2 * b + (aggp[0] ? 0 : 1)];
  needed[node] = 1;                       // benign race (same value)
  int old = atomicCAS(&sel_map[node], -1, -2);
  if (old == -1) {
    int c = atomicAdd(&cnt[0], 1);
    sel_map[node] = c;
    node_list[c] = node;
  }
}

// ---------------- count edges + mark sources + last-block scan -----------------
__global__ void count_scan(const int* __restrict__ ei, const int* __restrict__ sel_map,
                           int* __restrict__ deg, int* __restrict__ needed,
                           int* __restrict__ cnt, int* __restrict__ offs) {
  int e = blockIdx.x * 256 + threadIdx.x;
  if (e < E) {
    int d = sel_map[ei[E + e]];
    if (d >= 0) {
      atomicAdd(&deg[d], 1);
      needed[ei[e]] = 1;                  // benign race
    }
  }
  __shared__ int islast;
  __syncthreads();
  if (threadIdx.x == 0) {
    __threadfence();
    islast = (atomicAdd(&cnt[2], 1) == (int)gridDim.x - 1) ? 1 : 0;
  }
  __syncthreads();
  if (!islast) return;
  // last block: exclusive scan of deg[0..4095] -> offs[0..4096]
  __shared__ int psum[256];
  int tid = threadIdx.x;
  int base = tid * 16;
  int loc[16];
  int s = 0;
  #pragma unroll
  for (int j = 0; j < 16; j++) { loc[j] = atomicAdd(&deg[base + j], 0); s += loc[j]; }
  psum[tid] = s;
  __syncthreads();
  for (int off = 1; off < 256; off <<= 1) {
    int tmp = (tid >= off) ? psum[tid - off] : 0;
    __syncthreads();
    psum[tid] += tmp;
    __syncthreads();
  }
  int run = psum[tid] - s;
  #pragma unroll
  for (int j = 0; j < 16; j++) { offs[base + j] = run; run += loc[j]; }
  if (tid == 255) offs[NB] = run;
}

// ---------------- scatter edges + build compact row list -----------------------
__global__ void scatter_rows(const int* __restrict__ ei, const int* __restrict__ sel_map,
                             const int* __restrict__ offs, int* __restrict__ cursor,
                             int* __restrict__ es_sorted,
                             const int* __restrict__ needed, int* __restrict__ rowid,
                             int* __restrict__ rowlist, int* __restrict__ cnt) {
  if (blockIdx.x < (E + 255) / 256) {
    int e = blockIdx.x * 256 + threadIdx.x;
    if (e >= E) return;
    int d = sel_map[ei[E + e]];
    if (d >= 0) {
      int p = atomicAdd(&cursor[d], 1);
      es_sorted[offs[d] + p] = ei[e];
    }
  } else {
    int n = (blockIdx.x - (E + 255) / 256) * 256 + threadIdx.x;
    if (n >= N) return;
    if (needed[n]) {
      int r = atomicAdd(&cnt[1], 1);
      rowid[n] = r;
      rowlist[r] = n;
    }
  }
}

// ---------------- lin1 on compact rows + fused score ---------------------------
// Block = 4 waves x 32 rows = 128 rows, 128 cols. B LDS-staged in 4 stages of
// 64 k (32 KB, swizzled straight-copy). A fp32 gathered by rowlist, trunc-split.
__global__ __launch_bounds__(256)
void gemm_lin1(const float* __restrict__ a0, const float* __restrict__ a1,
               const unsigned short* __restrict__ Bth,
               const unsigned short* __restrict__ Btl,
               const float* __restrict__ bias, float* __restrict__ xp,
               const float* __restrict__ wvec,
               float* __restrict__ s_src, float* __restrict__ s_dst,
               const int* __restrict__ rowlist, const int* __restrict__ cnt) {
  __shared__ unsigned short BsH[8192];   // one stage: 16 tiles x 512
  __shared__ unsigned short BsL[8192];
  const int rcnt = cnt[1];
  if (blockIdx.x * 128 >= rcnt) return;
  const int t = threadIdx.x, lane = t & 63, wave = t >> 6;
  const int nl = lane & 15, quad = lane >> 4;
  const int rt = blockIdx.x * 128 + wave * 32;

  int node[2];
  #pragma unroll
  for (int i = 0; i < 2; i++) {
    int r = rt + i * 16 + nl;
    node[i] = (r < rcnt) ? rowlist[r] : -1;
  }

  f32x4 acc[2][8];
  #pragma unroll
  for (int i = 0; i < 2; i++)
    #pragma unroll
    for (int c = 0; c < 8; c++) acc[i][c] = (f32x4){0.f, 0.f, 0.f, 0.f};

  for (int st = 0; st < 4; st++) {
    // stage B tiles [st*16, st*16+16) : straight swizzled copy, coalesced
    {
      int sb = st * 8192;
      #pragma unroll
      for (int u = 0; u < 4; u++) {
        int o = (u * 256 + t) * 8;
        *(bf16x8*)&BsH[o] = *(const bf16x8*)(Bth + sb + o);
        *(bf16x8*)&BsL[o] = *(const bf16x8*)(Btl + sb + o);
      }
    }
    __syncthreads();
    #pragma unroll
    for (int u = 0; u < 2; u++) {
      const int kt = st * 2 + u;
      const float* A = (kt < 4) ? a0 : a1;
      const int kk = (kt & 3) * 32 + quad * 8;
      bf16x8 ahi[2], alo[2];
      #pragma unroll
      for (int i = 0; i < 2; i++) {
        float4 v0 = make_float4(0.f, 0.f, 0.f, 0.f), v1 = v0;
        if (node[i] >= 0) {
          const float* p = A + (size_t)node[i] * H + kk;
          v0 = *(const float4*)p;
          v1 = *(const float4*)(p + 4);
        }
        float af[8] = {v0.x, v0.y, v0.z, v0.w, v1.x, v1.y, v1.z, v1.w};
        #pragma unroll
        for (int j = 0; j < 8; j++) {
          short h_, l_;
          split_trunc(af[j], &h_, &l_);
          ahi[i][j] = h_;
          alo[i][j] = l_;
        }
      }
      #pragma unroll
      for (int c = 0; c < 8; c++) {
        int off = ((u * 8 + c) * 64 + lane) * 8;
        bf16x8 bh = *(const bf16x8*)&BsH[off];
        bf16x8 bl = *(const bf16x8*)&BsL[off];
        #pragma unroll
        for (int i = 0; i < 2; i++) { MFMA3(acc[i][c], ahi[i], alo[i], bh, bl); }
      }
    }
    __syncthreads();
  }

  // epilogue: bias, store x', fused score
  float bv[8], wvf[6][8];
  #pragma unroll
  for (int c = 0; c < 8; c++) {
    int col = c * 16 + nl;
    bv[c] = bias[col];
    #pragma unroll
    for (int v6 = 0; v6 < 6; v6++) wvf[v6][c] = wvec[v6 * 128 + col];
  }
  #pragma unroll
  for (int i = 0; i < 2; i++)
    #pragma unroll
    for (int r = 0; r < 4; r++) {
      int row = rt + i * 16 + quad * 4 + r;
      if (row >= rcnt) continue;
      float* cr = xp + (size_t)row * H;
      float sc[6] = {0.f, 0.f, 0.f, 0.f, 0.f, 0.f};
      #pragma unroll
      for (int c = 0; c < 8; c++) {
        float val = acc[i][c][r] + bv[c];
        cr[c * 16 + nl] = val;
        #pragma unroll
        for (int v6 = 0; v6 < 6; v6++) sc[v6] = fmaf(val, wvf[v6][c], sc[v6]);
      }
      #pragma unroll
      for (int m = 1; m < 16; m <<= 1)
        #pragma unroll
        for (int v6 = 0; v6 < 6; v6++) sc[v6] += __shfl_xor(sc[v6], m);
      if (nl == 0) {
        #pragma unroll
        for (int h3 = 0; h3 < 3; h3++) {
          s_src[h3 * RCAP + row] = sc[2 * h3 + 0];
          s_dst[h3 * RCAP + row] = sc[2 * h3 + 1];
        }
      }
    }
}

// ---------------- GAT aggregation (no max pass; scores bounded by construction)
__global__ __launch_bounds__(128)
void gat_node_kernel(const int* __restrict__ node_list, const int* __restrict__ cnt,
                     const int* __restrict__ offs, const int* __restrict__ es_sorted,
                     const int* __restrict__ rowid,
                     const float* __restrict__ xp, const float* __restrict__ s_src,
                     const float* __restrict__ s_dst,
                     unsigned short* __restrict__ aggxh, unsigned short* __restrict__ aggxl,
                     unsigned short* __restrict__ xsh, unsigned short* __restrict__ xsl) {
  int c = blockIdx.x;
  if (c >= cnt[0]) return;
  int t = threadIdx.x;
  int n = node_list[c];
  int rn = rowid[n];
  {
    float xv = xp[(size_t)rn * H + t];
    unsigned short vh, vl;
    split_rne(xv, vh, vl);
    xsh[(size_t)c * H + t] = vh;
    xsl[(size_t)c * H + t] = vl;
  }
  float sd0 = s_dst[0 * RCAP + rn], sd1 = s_dst[1 * RCAP + rn], sd2 = s_dst[2 * RCAP + rn];
  int e0 = offs[c], e1 = offs[c + 1];
  __shared__ float exs[3][128];
  __shared__ int rss[128];
  float u0 = 0.f, u1 = 0.f, u2 = 0.f, z0 = 0.f, z1 = 0.f, z2 = 0.f;
  for (int base = e0; base < e1; base += 128) {
    int e = base + t;
    if (e < e1) {
      int s = es_sorted[e];
      int rs = rowid[s];
      rss[t] = rs;
      exs[0][t] = __expf(lrelu(s_src[0 * RCAP + rs] + sd0));
      exs[1][t] = __expf(lrelu(s_src[1 * RCAP + rs] + sd1));
      exs[2][t] = __expf(lrelu(s_src[2 * RCAP + rs] + sd2));
    }
    __syncthreads();
    int m = min(128, e1 - base);
    for (int j = 0; j < m; j++) {
      float xs = xp[(size_t)rss[j] * H + t];
      float ex0 = exs[0][j], ex1 = exs[1][j], ex2 = exs[2][j];
      z0 += ex0; z1 += ex1; z2 += ex2;
      u0 = fmaf(ex0, xs, u0); u1 = fmaf(ex1, xs, u1); u2 = fmaf(ex2, xs, u2);
    }
    __syncthreads();
  }
  size_t cb = (size_t)c * H + t;
  bool any = e1 > e0;
  float v0 = any ? u0 / z0 : 0.f;
  float v1 = any ? u1 / z1 : 0.f;
  float v2 = any ? u2 / z2 : 0.f;
  unsigned short vh, vl;
  split_rne(v0, vh, vl); aggxh[0 * ((size_t)NB * H) + cb] = vh; aggxl[0 * ((size_t)NB * H) + cb] = vl;
  split_rne(v1, vh, vl); aggxh[1 * ((size_t)NB * H) + cb] = vh; aggxl[1 * ((size_t)NB * H) + cb] = vl;
  split_rne(v2, vh, vl); aggxh[2 * ((size_t)NB * H) + cb] = vh; aggxl[2 * ((size_t)NB * H) + cb] = vl;
}

// ---------------- all 3 hops + lin2, fully fused (depth phase is row-local) ----
// Block = 16 rows; grid 256. LSTM h (bf16 pair) + c (f32) live in LDS only.
__global__ __launch_bounds__(256)
void hop_all(const unsigned short* __restrict__ aggxh, const unsigned short* __restrict__ aggxl,
             const unsigned short* __restrict__ xsh, const unsigned short* __restrict__ xsl,
             const unsigned short* __restrict__ whi, const unsigned short* __restrict__ wlo,
             const float* __restrict__ gat_b, const float* __restrict__ lstm_b,
             const float* __restrict__ lin2_b, float* __restrict__ l2out) {
  __shared__ unsigned short HtH[16 * 136], HtL[16 * 136];   // htmp pair
  __shared__ unsigned short HsH[16 * 136], HsL[16 * 136];   // h pair
  __shared__ float Cst[16 * 128];                           // c state
  const int t = threadIdx.x, lane = t & 63, wave = t >> 6;
  const int nl = lane & 15, quad = lane >> 4;
  const int r0 = blockIdx.x * 16;

  for (int i = t; i < 16 * 136; i += 256) { HsH[i] = 0; HsL[i] = 0; }
  for (int i = t; i < 16 * 128; i += 256) Cst[i] = 0.f;
  __syncthreads();

  for (int hop = 0; hop < HOPS; hop++) {
    const unsigned short* agh = aggxh + (size_t)hop * NB * H;
    const unsigned short* agl = aggxl + (size_t)hop * NB * H;
    const unsigned short* gWh = whi + WOFF_GAT + hop * 16384;
    const unsigned short* gWl = wlo + WOFF_GAT + hop * 16384;
    const unsigned short* CWh = whi + WOFF_CAT + hop * 196608;
    const unsigned short* CWl = wlo + WOFF_CAT + hop * 196608;
    const float* gbias = gat_b + hop * H;
    const float* lbias = lstm_b + hop * 512;

    // GEMM1: htmp = tanh(aggx @ gatW + b); wave: 16 rows x 32 cols
    f32x4 acc1[2];
    #pragma unroll
    for (int j = 0; j < 2; j++) acc1[j] = (f32x4){0.f, 0.f, 0.f, 0.f};
    #pragma unroll
    for (int kt = 0; kt < 4; kt++) {
      size_t aoff = (size_t)(r0 + nl) * H + kt * 32 + quad * 8;
      bf16x8 ah = *(const bf16x8*)(agh + aoff);
      bf16x8 al = *(const bf16x8*)(agl + aoff);
      #pragma unroll
      for (int j = 0; j < 2; j++) {
        size_t boff = ((size_t)(kt * 8 + 2 * wave + j) * 64 + lane) * 8;
        bf16x8 bh = *(const bf16x8*)(gWh + boff);
        bf16x8 bl = *(const bf16x8*)(gWl + boff);
        MFMA3(acc1[j], ah, al, bh, bl);
      }
    }
    #pragma unroll
    for (int j = 0; j < 2; j++) {
      int col = wave * 32 + j * 16 + nl;
      float bv = gbias[col];
      #pragma unroll
      for (int r = 0; r < 4; r++) {
        int rl = quad * 4 + r;
        float v = tanhf(acc1[j][r] + bv);
        unsigned short vh, vl2;
        split_rne(v, vh, vl2);
        HtH[rl * 136 + col] = vh;
        HtL[rl * 136 + col] = vl2;
      }
    }
    __syncthreads();

    // GEMM2: permuted gates [16 x 384] @ [384 x 512]; wave: 8 col-tiles
    f32x4 acc2[8];
    #pragma unroll
    for (int j = 0; j < 8; j++) acc2[j] = (f32x4){0.f, 0.f, 0.f, 0.f};
    for (int kt = 0; kt < 12; kt++) {
      int kk = (kt & 3) * 32 + quad * 8;
      bf16x8 ah, al;
      if (kt < 4) {
        ah = *(const bf16x8*)&HtH[nl * 136 + kk];
        al = *(const bf16x8*)&HtL[nl * 136 + kk];
      } else if (kt < 8 && hop == 0) {
        size_t aoff = (size_t)(r0 + nl) * H + kk;
        ah = *(const bf16x8*)(xsh + aoff);
        al = *(const bf16x8*)(xsl + aoff);
      } else {  // x1 = h (hops 1,2) and third segment h (all hops)
        ah = *(const bf16x8*)&HsH[nl * 136 + kk];
        al = *(const bf16x8*)&HsL[nl * 136 + kk];
      }
      #pragma unroll
      for (int cc = 0; cc < 8; cc++) {
        size_t boff = ((size_t)(kt * 32 + 8 * wave + cc) * 64 + lane) * 8;
        bf16x8 bh = *(const bf16x8*)(CWh + boff);
        bf16x8 bl = *(const bf16x8*)(CWl + boff);
        MFMA3(acc2[cc], ah, al, bh, bl);
      }
    }
    __syncthreads();   // h reads done before h writes

    // LSTM pointwise; lane owns all 4 gates of its features
    #pragma unroll
    for (int ft = 0; ft < 2; ft++) {
      int f = (2 * wave + ft) * 16 + nl;
      float b_i = lbias[0 * 128 + f], b_f = lbias[1 * 128 + f];
      float b_g = lbias[2 * 128 + f], b_o = lbias[3 * 128 + f];
      #pragma unroll
      for (int r = 0; r < 4; r++) {
        int rl = quad * 4 + r;
        float gi = acc2[ft * 4 + 0][r] + b_i;
        float gf = acc2[ft * 4 + 1][r] + b_f;
        float gg = acc2[ft * 4 + 2][r] + b_g;
        float go = acc2[ft * 4 + 3][r] + b_o;
        float cp = Cst[rl * 128 + f];
        float cn = sigmoidf_(gf) * cp + sigmoidf_(gi) * tanhf(gg);
        float hn = sigmoidf_(go) * tanhf(cn);
        Cst[rl * 128 + f] = cn;
        unsigned short vh, vl2;
        split_rne(hn, vh, vl2);
        HsH[rl * 136 + f] = vh;
        HsL[rl * 136 + f] = vl2;
      }
    }
    __syncthreads();
  }

  // lin2 on final h; wave: 16 rows x 32 cols
  f32x4 acc3[2];
  #pragma unroll
  for (int j = 0; j < 2; j++) acc3[j] = (f32x4){0.f, 0.f, 0.f, 0.f};
  #pragma unroll
  for (int kt = 0; kt < 4; kt++) {
    int kk = kt * 32 + quad * 8;
    bf16x8 ah = *(const bf16x8*)&HsH[nl * 136 + kk];
    bf16x8 al = *(const bf16x8*)&HsL[nl * 136 + kk];
    #pragma unroll
    for (int j = 0; j < 2; j++) {
      size_t boff = ((size_t)(kt * 8 + 2 * wave + j) * 64 + lane) * 8;
      bf16x8 bh = *(const bf16x8*)(whi + WOFF_L2 + boff);
      bf16x8 bl = *(const bf16x8*)(wlo + WOFF_L2 + boff);
      MFMA3(acc3[j], ah, al, bh, bl);
    }
  }
  #pragma unroll
  for (int j = 0; j < 2; j++) {
    int col = wave * 32 + j * 16 + nl;
    float bv = lin2_b[col];
    #pragma unroll
    for (int r = 0; r < 4; r++) {
      int row = r0 + quad * 4 + r;
      l2out[(size_t)row * H + col] = acc3[j][r] + bv;
    }
  }
}

// ---------------- output gather ------------------------------------------------
__global__ void scatter_out(const float* __restrict__ l2out, const int* __restrict__ sel_map,
                            const int* __restrict__ root, const int* __restrict__ aggp,
                            float* __restrict__ out) {
  int id = blockIdx.x * 256 + threadIdx.x;
  if (id >= NB * H) return;
  int b = id >> 7, f = id & 127;
  int node = root[2 * b + (aggp[0] ? 0 : 1)];
  int c = sel_map[node];
  out[id] = l2out[(size_t)c * H + f];
}

// ==============================================================================
extern "C" void kernel_launch(void* const* d_in, const int* in_sizes, int n_in,
                              void* d_out, int out_size, void* d_ws, size_t ws_size,
                              hipStream_t stream) {
  const float* node_feat = (const float*)d_in[0];
  const float* send_embd = (const float*)d_in[1];
  const int*   edge_idx  = (const int*)d_in[2];
  const int*   root_idx  = (const int*)d_in[3];
  const int*   aggp      = (const int*)d_in[4];
  const float* lin1_W    = (const float*)d_in[5];
  const float* lin1_b    = (const float*)d_in[6];
  const float* gat_W     = (const float*)d_in[7];
  const float* gat_asrc  = (const float*)d_in[8];
  const float* gat_adst  = (const float*)d_in[9];
  const float* gat_b     = (const float*)d_in[10];
  const float* lstm_Wih  = (const float*)d_in[11];
  const float* lstm_Whh  = (const float*)d_in[12];
  const float* lstm_b    = (const float*)d_in[13];
  const float* lin2_W    = (const float*)d_in[14];
  const float* lin2_b    = (const float*)d_in[15];
  float* out = (float*)d_out;

  char* ws = (char*)d_ws;
  float* xp      = (float*)(ws + OFF_XP);
  float* s_src   = (float*)(ws + OFF_SSRC);
  float* s_dst   = (float*)(ws + OFF_SDST);
  float* wvec    = (float*)(ws + OFF_WVEC);
  int*   sel_map = (int*)(ws + OFF_SELMAP);
  int*   needed  = (int*)(ws + OFF_NEEDED);
  int*   rowid   = (int*)(ws + OFF_ROWID);
  int*   nodelst = (int*)(ws + OFF_NODELST);
  int*   rowlst  = (int*)(ws + OFF_ROWLST);
  int*   cnt     = (int*)(ws + OFF_CNT);
  int*   deg     = (int*)(ws + OFF_DEG);
  int*   offs    = (int*)(ws + OFF_OFFS);
  int*   cursor  = (int*)(ws + OFF_CURSOR);
  int*   esort   = (int*)(ws + OFF_ESORT);
  unsigned short* aggxh = (unsigned short*)(ws + OFF_AGGXH);
  unsigned short* aggxl = (unsigned short*)(ws + OFF_AGGXL);
  unsigned short* xsh   = (unsigned short*)(ws + OFF_XSH);
  unsigned short* xsl   = (unsigned short*)(ws + OFF_XSL);
  float* l2out   = (float*)(ws + OFF_L2OUT);
  unsigned short* whi = (unsigned short*)(ws + OFF_WHI);
  unsigned short* wlo = (unsigned short*)(ws + OFF_WLO);

  const int EB = (E + 255) / 256;   // 6250
  const int NBK = (N + 255) / 256;  // 391

  mega_prep<<<6 + WCONV_BLOCKS + 256, 256, 0, stream>>>(
      gat_W, gat_asrc, gat_adst, wvec, lin1_W, lstm_Wih, lstm_Whh, lin2_W,
      whi, wlo, sel_map, needed, deg, cursor, cnt);
  roots_assign<<<(NB + 255) / 256, 256, 0, stream>>>(root_idx, aggp, sel_map,
                                                     nodelst, cnt, needed);
  count_scan<<<EB, 256, 0, stream>>>(edge_idx, sel_map, deg, needed, cnt, offs);
  scatter_rows<<<EB + NBK, 256, 0, stream>>>(edge_idx, sel_map, offs, cursor, esort,
                                             needed, rowid, rowlst, cnt);
  gemm_lin1<<<RCAP / 128, 256, 0, stream>>>(
      node_feat, send_embd, whi + WOFF_L1, wlo + WOFF_L1, lin1_b, xp,
      wvec, s_src, s_dst, rowlst, cnt);
  gat_node_kernel<<<NB, 128, 0, stream>>>(nodelst, cnt, offs, esort, rowid,
                                          xp, s_src, s_dst, aggxh, aggxl, xsh, xsl);
  hop_all<<<NB / 16, 256, 0, stream>>>(aggxh, aggxl, xsh, xsl, whi, wlo,
                                       gat_b, lstm_b, lin2_b, l2out);
  scatter_out<<<(NB * H + 255) / 256, 256, 0, stream>>>(l2out, sel_map, root_idx,
                                                        aggp, out);
}